// Round 12
// baseline (3326.637 us; speedup 1.0000x reference)
//
#include <hip/hip_runtime.h>

#define B_ 256
#define T_ 512
#define H_ 512
#define P_ 128
#define G4 2048   // 4*H

typedef __attribute__((ext_vector_type(8))) _Float16 h8_t;
typedef __attribute__((ext_vector_type(4))) float floatx4;
typedef __attribute__((ext_vector_type(4))) unsigned u32x4;

__device__ __forceinline__ float sigm(float x){ return 1.0f / (1.0f + __expf(-x)); }
__device__ __forceinline__ float tanh_(float x){ return 2.0f / (1.0f + __expf(-2.0f*x)) - 1.0f; }
__device__ __forceinline__ unsigned short f2h(float f){
  union { _Float16 h; unsigned short u; } c; c.h = (_Float16)f; return c.u;
}
__device__ __forceinline__ float wredsum(float v){
  #pragma unroll
  for (int off = 32; off; off >>= 1) v += __shfl_xor(v, off, 64);
  return v;
}

// Pack enc_Whh (2048x512 fp32 row-major [gate_col][k]) into fp16 MFMA B-frag
// order. tile = (cg*4 + w)*2 + ct; element = tile*8192 + kt*512 + lane*8 + e.
// In-tile col = q*4 + dhc  ->  Whh row = q*512 + cg*32 + w*8 + ct*4 + dhc
// k = kt*32 + (lane>>4)*8 + e
__global__ __launch_bounds__(256) void pack_w(const float* __restrict__ Whh,
                                              unsigned short* __restrict__ Wp){
  int p8   = blockIdx.x * 256 + threadIdx.x;   // 0..131071
  int lane = p8 & 63;
  int kt   = (p8 >> 6) & 15;
  int ct   = (p8 >> 10) & 1;
  int w    = (p8 >> 11) & 3;
  int cg   = (p8 >> 13) & 15;
  int q    = (lane & 15) >> 2, dhc = lane & 3;
  int col  = q*512 + cg*32 + w*8 + ct*4 + dhc;
  int k0   = kt*32 + (lane >> 4)*8;
  const float* s = Whh + (size_t)col * H_ + k0;
  unsigned short v[8];
  #pragma unroll
  for (int e = 0; e < 8; e++) v[e] = f2h(s[e]);
  *(uint4*)(Wp + (size_t)p8 * 8) = *(const uint4*)v;
}

// Persistent encoder: 256 blocks = 16 groups (16 batch rows) x 16 cg (32 hc
// cols). Exchange: TAGGED-DIRECT, congestion-lean.
//   word(g,row,hp,cg) = {tag=t+1 (32b) | 2 x fp16 h}  at
//   D[parity][g*4096 + (row*16+hp)*16 + cg]  -> each consumer thread's 16
//   words are CONTIGUOUS (128B): polled as 8 x dwordx4 (2 words/transaction).
//   Producer: ONE global_store_dwordx2 sc0 sc1 per thread (write-through to
//   IF$, no atomic serialization, no drain, no summary, no bulk phase).
//   Tag travels WITH data -> zero ordering round-trips; visibility failure
//   only costs retries, never correctness. Skew <= 1 step (R5 argument);
//   both parities memset in-graph (replay safety).
__global__ __launch_bounds__(256) void enc_persist(
    const unsigned short* __restrict__ Wp,
    const float* __restrict__ x,
    const float* __restrict__ Wih,
    const float* __restrict__ bih,
    const float* __restrict__ bhh,
    unsigned long long* __restrict__ D,   // [2 parity][16 g][4096 words]
    float* __restrict__ hfp,
    float* __restrict__ cfin,
    float* __restrict__ G,
    int zf)
{
  __shared__ float x_lds[16][512];      // 32 KB
  __shared__ uint4 A_lds4[1024];        // 16 KB, XOR-swizzled fp16 A tile
  __shared__ float Sg[4][16][33];       // 8448 B
  __shared__ char pad_[30000];          // total 87.6 KB > 80 KB => 1 block/CU

  char* A_lds = (char*)A_lds4;
  const int bid = blockIdx.x;
  const int tid = threadIdx.x;
  const int lane = tid & 63, wv = tid >> 6;

  if (zf){ pad_[tid] = (char)Wih[tid]; if (!tid) A_lds[0] = pad_[128]; }

  const int g  = bid >> 4;              // batch group (rows g*16..+15)
  const int cg = bid & 15;              // col group   (hc cg*32..+31)

  // ---- W fragments into registers (once): 128 regs/wave
  h8_t wreg[2][16];
  {
    const unsigned short* wb = Wp + (size_t)((cg*4 + wv)*2) * 8192;
    #pragma unroll
    for (int ct = 0; ct < 2; ct++)
      #pragma unroll
      for (int kt = 0; kt < 16; kt++)
        wreg[ct][kt] = *(const h8_t*)(wb + (ct*16 + kt)*512 + lane*8);
  }
  // ---- stage x rows (once)
  #pragma unroll
  for (int i = 0; i < 8; i++){
    int idx = tid + i*256;
    int r = idx >> 7, c4 = (idx & 127)*4;
    *(float4*)&x_lds[r][c4] = *(const float4*)&x[(size_t)(g*16 + r)*T_ + c4];
  }
  // ---- per-thread epilogue: one row (erow), two adjacent hc
  const int erow = tid >> 4;            // 0..15
  const int hp   = tid & 15;            // col-pair slot within block
  const int hc0  = cg*32 + hp*2;
  float wih0[4], wih1[4], bs0[4], bs1[4];
  #pragma unroll
  for (int q = 0; q < 4; q++){
    wih0[q] = Wih[q*512 + hc0];     wih1[q] = Wih[q*512 + hc0 + 1];
    bs0[q]  = bih[q*512 + hc0]     + bhh[q*512 + hc0];
    bs1[q]  = bih[q*512 + hc0 + 1] + bhh[q*512 + hc0 + 1];
  }
  float cr0 = 0.f, cr1 = 0.f;

  // ---- maps. Consumer thread (erow,hp): 16 contiguous words (one per
  // producer cgp); word cgp carries h pair for col cgp*32 + hp*2.
  // LDS byte for that pair: erow*1024 + ((cgp*64 + hp*4) ^ rxor_st).
  const int rxor_st = (erow & 7) << 4;
  int lws[16];
  #pragma unroll
  for (int cgp = 0; cgp < 16; cgp++)
    lws[cgp] = erow*1024 + ((cgp*64 + hp*4) ^ rxor_st);
  const size_t Xrow = (size_t)g*4096 + (size_t)(erow*16 + hp)*16;
  const size_t pidx = Xrow + cg;        // my word (I am producer cg)
  const int arow = lane & 15, ahalf = lane >> 4;
  const int rxor = (arow & 7) << 4;

  unsigned mypay = 0u;                  // my pair of h(-1) = 0

  for (int t = 0; t <= T_; t++){
    // ---- acquire h(t-1): parity (t+1)&1, tag == t; poll 8 x dwordx4
    const unsigned long long* Xp = D + (size_t)((t+1)&1)*65536 + Xrow;
    const unsigned wtag = (unsigned)t;
    *(unsigned*)(A_lds + lws[cg]) = mypay;      // self word from registers
    unsigned pend = 0xFFFFu & ~(1u << cg);
    while (pend){
      u32x4 qd[8];
      #pragma unroll
      for (int q = 0; q < 8; q++){
        if (pend & (3u << (q*2)))
          asm volatile("global_load_dwordx4 %0, %1, off sc0 sc1"
                       : "=v"(qd[q]) : "v"(Xp + q*2));
      }
      asm volatile("s_waitcnt vmcnt(0)" ::: "memory");
      __builtin_amdgcn_sched_barrier(0);
      #pragma unroll
      for (int q = 0; q < 8; q++){
        if (pend & (1u << (q*2)))
          if (qd[q][1] == wtag){
            *(unsigned*)(A_lds + lws[2*q]) = qd[q][0];
            pend &= ~(1u << (q*2));
          }
        if (pend & (1u << (q*2+1)))
          if (qd[q][3] == wtag){
            *(unsigned*)(A_lds + lws[2*q+1]) = qd[q][2];
            pend &= ~(1u << (q*2+1));
          }
      }
    }
    __syncthreads();

    floatx4 acc0 = {0,0,0,0}, acc1 = {0,0,0,0};
    h8_t a[16];
    #pragma unroll
    for (int kt = 0; kt < 16; kt++)
      a[kt] = *(const h8_t*)(A_lds + arow*1024 + ((kt*64 + ahalf*16) ^ rxor));
    #pragma unroll
    for (int kt = 0; kt < 16; kt++){
      acc0 = __builtin_amdgcn_mfma_f32_16x16x32_f16(a[kt], wreg[0][kt], acc0, 0,0,0);
      acc1 = __builtin_amdgcn_mfma_f32_16x16x32_f16(a[kt], wreg[1][kt], acc1, 0,0,0);
    }
    // C/D: col = lane&15 (= q*4+dhc), row = (lane>>4)*4 + r
    #pragma unroll
    for (int r = 0; r < 4; r++){
      int srow = ahalf*4 + r;
      int q = (lane & 15) >> 2, dhc = lane & 3;
      Sg[q][srow][wv*8 + dhc]     = acc0[r];
      Sg[q][srow][wv*8 + 4 + dhc] = acc1[r];
    }
    __syncthreads();

    if (t == T_){   // Gconst = h(511)@Whh^T + bsum
      int b = g*16 + erow;
      #pragma unroll
      for (int q = 0; q < 4; q++){
        G[(size_t)b*G4 + q*512 + hc0]     = Sg[q][erow][hp*2]     + bs0[q];
        G[(size_t)b*G4 + q*512 + hc0 + 1] = Sg[q][erow][hp*2 + 1] + bs1[q];
      }
      break;
    }

    const float xb = x_lds[erow][t];
    float pi0 = Sg[0][erow][hp*2] + xb*wih0[0] + bs0[0];
    float pf0 = Sg[1][erow][hp*2] + xb*wih0[1] + bs0[1];
    float pg0 = Sg[2][erow][hp*2] + xb*wih0[2] + bs0[2];
    float po0 = Sg[3][erow][hp*2] + xb*wih0[3] + bs0[3];
    float c20 = sigm(pf0)*cr0 + sigm(pi0)*tanh_(pg0);
    float h0  = sigm(po0)*tanh_(c20);  cr0 = c20;

    float pi1 = Sg[0][erow][hp*2+1] + xb*wih1[0] + bs1[0];
    float pf1 = Sg[1][erow][hp*2+1] + xb*wih1[1] + bs1[1];
    float pg1 = Sg[2][erow][hp*2+1] + xb*wih1[2] + bs1[2];
    float po1 = Sg[3][erow][hp*2+1] + xb*wih1[3] + bs1[3];
    float c21 = sigm(pf1)*cr1 + sigm(pi1)*tanh_(pg1);
    float h1  = sigm(po1)*tanh_(c21);  cr1 = c21;

    // ---- publish h(t): ONE tagged sc0+sc1 store (write-through), no drain
    mypay = (unsigned)f2h(h0) | ((unsigned)f2h(h1) << 16);
    {
      unsigned long long wo = ((unsigned long long)(t + 1) << 32) | mypay;
      unsigned long long* pw = D + (size_t)(t & 1)*65536 + pidx;
      asm volatile("global_store_dwordx2 %0, %1, off sc0 sc1"
                   :: "v"(pw), "v"(wo) : "memory");
    }

    if (t == T_-1){
      int b = g*16 + erow;
      hfp[(size_t)b*512 + hc0]     = h0;  hfp[(size_t)b*512 + hc0 + 1] = h1;
      cfin[(size_t)b*512 + hc0]    = c20; cfin[(size_t)b*512 + hc0 + 1] = c21;
    }
  }
}

// Decoder: scalar recurrence per batch row, one wave per row, zero syncs.
__global__ __launch_bounds__(256) void decoder(
    const float* __restrict__ G, const float* __restrict__ c,
    const float* __restrict__ hfp, const float* __restrict__ Wih,
    const float* __restrict__ dW, const float* __restrict__ db,
    float* __restrict__ out)
{
  const int row  = blockIdx.x * 4 + (threadIdx.x >> 6);
  const int lane = threadIdx.x & 63;
  float Gr[4][8], wr[4][8], cc[8], wd[8];
  float p = 0.f;
  #pragma unroll
  for (int k = 0; k < 8; k++){
    int j = lane + k*64;
    cc[k] = c[(size_t)row*H_ + j];
    wd[k] = dW[j];
    #pragma unroll
    for (int q = 0; q < 4; q++){
      Gr[q][k] = G[(size_t)row*G4 + q*512 + j];
      wr[q][k] = Wih[q*512 + j];
    }
    p += hfp[(size_t)row*H_ + j] * wd[k];
  }
  const float bias = db[0];
  float y = wredsum(p) + bias;
  for (int tt = 0; tt < P_; tt++){
    if (lane == 0) out[(size_t)row*P_ + tt] = y;
    if (tt == P_-1) break;
    float pp = 0.f;
    #pragma unroll
    for (int k = 0; k < 8; k++){
      float i_ = sigm (y*wr[0][k] + Gr[0][k]);
      float f_ = sigm (y*wr[1][k] + Gr[1][k]);
      float g_ = tanh_(y*wr[2][k] + Gr[2][k]);
      float o_ = sigm (y*wr[3][k] + Gr[3][k]);
      float c2 = f_*cc[k] + i_*g_;
      pp += o_*tanh_(c2)*wd[k];
    }
    y = wredsum(pp) + bias;
  }
}

extern "C" void kernel_launch(void* const* d_in, const int* in_sizes, int n_in,
                              void* d_out, int out_size, void* d_ws, size_t ws_size,
                              hipStream_t stream)
{
  const float* x    = (const float*)d_in[0];
  const float* Wih  = (const float*)d_in[1];
  const float* Whh  = (const float*)d_in[2];
  const float* bih  = (const float*)d_in[3];
  const float* bhh  = (const float*)d_in[4];
  // d_in[5..8] = dec_* : provably unused by the reference output
  const float* dW   = (const float*)d_in[9];
  const float* db   = (const float*)d_in[10];
  float* out = (float*)d_out;

  unsigned short* Wp    = (unsigned short*)d_ws;               // 2 MB
  unsigned long long* D = (unsigned long long*)(Wp + 1048576); // 131072 u64 (1 MB)
  float* hfp  = (float*)(D + 131072);                          // 131072 f32
  float* cfin = hfp + 131072;                                  // 131072 f32
  float* G    = cfin + 131072;                                 // 524288 f32 (2 MB)

  // Clear BOTH parities (tag 0 == wanted tag at t=0, payload h(-1)=0;
  // in-graph every launch -> replay safe).
  hipMemsetAsync(D, 0, 131072 * sizeof(unsigned long long), stream);
  pack_w<<<512, 256, 0, stream>>>(Whh, Wp);
  enc_persist<<<256, 256, 0, stream>>>(Wp, x, Wih, bih, bhh, D,
                                       hfp, cfin, G, 0);
  decoder<<<64, 256, 0, stream>>>(G, cfin, hfp, Wih, dW, db, out);
}